// Round 3
// baseline (41068.561 us; speedup 1.0000x reference)
//
#include <hip/hip_runtime.h>
#include <hip/hip_bf16.h>
#include <hip/hip_cooperative_groups.h>
#include <stdint.h>

#define BS 64
#define TT 512
#define FEAT 1024
#define HID 1024
#define NWG 256
#define NTHR 512

namespace cg = cooperative_groups;

__device__ __forceinline__ float sigmoidf_(float x){ return 1.0f/(1.0f + __expf(-x)); }

__device__ __forceinline__ unsigned short f2bf(float f){
    __hip_bfloat16 h = __float2bfloat16(f);
    return *reinterpret_cast<unsigned short*>(&h);
}
__device__ __forceinline__ float bf2f(unsigned short u){
    __hip_bfloat16 h = *reinterpret_cast<__hip_bfloat16*>(&u);
    return __bfloat162float(h);
}

// ---------------- Phase 1: [xz|xr|xh] = x @ [wz_x|wr_x|w_x] + bias ----------------
// M=32768 (b,t flat), N=3072 (z|r|h), K=1024. 128x64 tile, k-chunk 32, 256 threads,
// 8x4 register blocking. xz/xr stored bf16 (validated: absmax 2^-9 passed), xh fp32
// directly into d_out (it is consumed at step t then overwritten by h_t).
__global__ __launch_bounds__(256) void p1_gemm(
    const float* __restrict__ x,
    const float* __restrict__ w_z, const float* __restrict__ w_r, const float* __restrict__ w,
    const float* __restrict__ bZ, const float* __restrict__ bR, const float* __restrict__ bH,
    unsigned short* __restrict__ xz16, unsigned short* __restrict__ xr16,
    float* __restrict__ xh)
{
    __shared__ float As[32][136];  // [kk][m-swizzled]
    __shared__ float Bs[32][72];   // [kk][n]

    const int m0   = blockIdx.x * 128;
    const int n0g  = blockIdx.y * 64;
    const int mat  = n0g >> 10;              // 0=z, 1=r, 2=h
    const int ncol = n0g & 1023;

    const float* Wm    = (mat==0) ? w_z : (mat==1) ? w_r : w;
    const float* Bbase = Wm + (size_t)HID*1024 + ncol;  // x-part rows [H, H+FEAT)
    const float* bias  = ((mat==0) ? bZ : (mat==1) ? bR : bH) + ncol;

    const int tid = threadIdx.x;
    const int tx = tid & 15, ty = tid >> 4;
    const int lm = tid >> 3;
    const int lk = (tid & 7) * 4;

    float acc[8][4];
    #pragma unroll
    for (int i=0;i<8;i++)
        #pragma unroll
        for (int j=0;j<4;j++) acc[i][j] = 0.f;

    for (int k0 = 0; k0 < 1024; k0 += 32) {
        #pragma unroll
        for (int h = 0; h < 4; ++h) {
            const int m = lm + 32*h;
            float4 a = *(const float4*)(x + (size_t)(m0+m)*1024 + k0 + lk);
            const float av[4] = {a.x, a.y, a.z, a.w};
            #pragma unroll
            for (int i=0;i<4;i++) {
                const int kk  = lk + i;
                const int col = m ^ (((kk>>2)&3) << 3);
                As[kk][col] = av[i];
            }
        }
        {
            const int kk = tid >> 3;
            const int nq = (tid & 7) * 4;
            float4 b0 = *(const float4*)(Bbase + (size_t)(k0+kk)*1024 + nq);
            float4 b1 = *(const float4*)(Bbase + (size_t)(k0+kk)*1024 + nq + 32);
            *(float4*)&Bs[kk][nq]      = b0;
            *(float4*)&Bs[kk][nq + 32] = b1;
        }
        __syncthreads();
        #pragma unroll
        for (int kk = 0; kk < 32; ++kk) {
            const int ablk = (ty ^ ((kk>>2)&3)) << 3;
            float4 a0 = *(const float4*)&As[kk][ablk];
            float4 a1 = *(const float4*)&As[kk][ablk + 4];
            float4 b4 = *(const float4*)&Bs[kk][tx*4];
            const float av[8] = {a0.x,a0.y,a0.z,a0.w,a1.x,a1.y,a1.z,a1.w};
            const float bv[4] = {b4.x,b4.y,b4.z,b4.w};
            #pragma unroll
            for (int i=0;i<8;i++)
                #pragma unroll
                for (int j=0;j<4;j++)
                    acc[i][j] = fmaf(av[i], bv[j], acc[i][j]);
        }
        __syncthreads();
    }

    float4 bb = *(const float4*)(bias + tx*4);
    const float badd[4] = {bb.x, bb.y, bb.z, bb.w};
    #pragma unroll
    for (int i=0;i<8;i++) {
        const int m = m0 + ty*8 + i;
        const size_t off = (size_t)m*1024 + ncol + tx*4;
        float v[4];
        #pragma unroll
        for (int j=0;j<4;j++) v[j] = acc[i][j] + badd[j];
        if (mat == 2) {
            float4 o; o.x=v[0]; o.y=v[1]; o.z=v[2]; o.w=v[3];
            *(float4*)(xh + off) = o;
        } else {
            unsigned short* dst = (mat==0) ? xz16 : xr16;
            ushort4 u; u.x=f2bf(v[0]); u.y=f2bf(v[1]); u.z=f2bf(v[2]); u.w=f2bf(v[3]);
            *(ushort4*)(dst + off) = u;
        }
    }
}

// ---------------- persistent scan: one kernel, 512 steps, 2 grid.sync per step ----
// 256 WGs x 512 thr (8 waves). WG w owns cols c0=4w..c0+3 of z, r AND hbar; its
// 48 KB weight slice lives in LDS for the whole scan. Waves split K 8-way (128 each).
__global__ __launch_bounds__(NTHR, 1) void scan_persist(
    const float* __restrict__ h0,
    const float* __restrict__ w_z, const float* __restrict__ w_r, const float* __restrict__ w,
    const unsigned short* __restrict__ xz16, const unsigned short* __restrict__ xr16,
    float* __restrict__ hT, float* __restrict__ rhT, float* __restrict__ out)
{
    cg::grid_group grid = cg::this_grid();

    __shared__ float lwz[1024*4];   // 16 KB  [k][c]
    __shared__ float lwr[1024*4];   // 16 KB
    __shared__ float lwh[1024*4];   // 16 KB
    __shared__ float part[8*8*64];  // 16 KB  [q][acc][b]
    __shared__ float zs[4*64];      //  1 KB  z for this WG's cols

    const int wg  = blockIdx.x;       // 0..255
    const int tid = threadIdx.x;      // 0..511
    const int c0  = wg * 4;
    const int q   = tid >> 6;         // wave 0..7 -> k-octant
    const int b   = tid & 63;

    // ---- prologue: weights -> LDS, h0 -> hT ----
    for (int k = tid; k < 1024; k += NTHR) {
        *(float4*)&lwz[k*4] = *(const float4*)(w_z + (size_t)k*1024 + c0);
        *(float4*)&lwr[k*4] = *(const float4*)(w_r + (size_t)k*1024 + c0);
        *(float4*)&lwh[k*4] = *(const float4*)(w   + (size_t)k*1024 + c0);
    }
    {
        const int g0 = wg * NTHR + tid;
        if (g0 < HID*BS) {
            const int bb = g0 >> 10, jj = g0 & 1023;
            hT[jj*64 + bb] = h0[g0];
        }
    }
    grid.sync();

    for (int t = 0; t < TT; ++t) {
        // ---------- phase A: z, r (and rh) ----------
        {
            float az0=0.f,az1=0.f,az2=0.f,az3=0.f;
            float ar0=0.f,ar1=0.f,ar2=0.f,ar3=0.f;
            const float*  hp  = hT + (size_t)(q*128)*64 + b;
            const float4* wzp = (const float4*)&lwz[(q*128)*4];
            const float4* wrp = (const float4*)&lwr[(q*128)*4];
            #pragma unroll 8
            for (int kk = 0; kk < 128; ++kk) {
                const float hk = hp[(size_t)kk*64];
                const float4 wz4 = wzp[kk];
                const float4 wr4 = wrp[kk];
                az0 = fmaf(hk, wz4.x, az0); az1 = fmaf(hk, wz4.y, az1);
                az2 = fmaf(hk, wz4.z, az2); az3 = fmaf(hk, wz4.w, az3);
                ar0 = fmaf(hk, wr4.x, ar0); ar1 = fmaf(hk, wr4.y, ar1);
                ar2 = fmaf(hk, wr4.z, ar2); ar3 = fmaf(hk, wr4.w, ar3);
            }
            part[(q*8+0)*64+b] = az0; part[(q*8+1)*64+b] = az1;
            part[(q*8+2)*64+b] = az2; part[(q*8+3)*64+b] = az3;
            part[(q*8+4)*64+b] = ar0; part[(q*8+5)*64+b] = ar1;
            part[(q*8+6)*64+b] = ar2; part[(q*8+7)*64+b] = ar3;
        }
        __syncthreads();
        {
            const int a  = tid >> 6;   // 0..3 -> z cols, 4..7 -> r cols (wave-uniform)
            const int bb = tid & 63;
            float s = 0.f;
            #pragma unroll
            for (int qq = 0; qq < 8; ++qq) s += part[(qq*8+a)*64+bb];
            if (a < 4) {
                const size_t xoff = ((size_t)bb*TT + t)*1024 + c0 + a;
                zs[a*64+bb] = sigmoidf_(s + bf2f(xz16[xoff]));
            } else {
                const int c = a - 4;
                const size_t xoff = ((size_t)bb*TT + t)*1024 + c0 + c;
                const float rv = sigmoidf_(s + bf2f(xr16[xoff]));
                rhT[(c0+c)*64 + bb] = rv * hT[(c0+c)*64 + bb];
            }
        }
        grid.sync();

        // ---------- phase B: hbar + h update ----------
        {
            float ah0=0.f,ah1=0.f,ah2=0.f,ah3=0.f;
            const float*  rp  = rhT + (size_t)(q*128)*64 + b;
            const float4* whp = (const float4*)&lwh[(q*128)*4];
            #pragma unroll 8
            for (int kk = 0; kk < 128; ++kk) {
                const float rk = rp[(size_t)kk*64];
                const float4 w4 = whp[kk];
                ah0 = fmaf(rk, w4.x, ah0); ah1 = fmaf(rk, w4.y, ah1);
                ah2 = fmaf(rk, w4.z, ah2); ah3 = fmaf(rk, w4.w, ah3);
            }
            part[(q*4+0)*64+b] = ah0; part[(q*4+1)*64+b] = ah1;
            part[(q*4+2)*64+b] = ah2; part[(q*4+3)*64+b] = ah3;
        }
        __syncthreads();
        if (tid < 256) {
            const int c  = tid >> 6;
            const int bb = tid & 63;
            float s = 0.f;
            #pragma unroll
            for (int qq = 0; qq < 8; ++qq) s += part[(qq*4+c)*64+bb];
            const size_t ooff = ((size_t)bb*TT + t)*1024 + c0 + c;
            const float hbar = tanhf(s + out[ooff]);      // out holds xh[b][t][j]
            const float zv   = zs[c*64+bb];
            const int   hoff = (c0+c)*64 + bb;
            const float hold = hT[hoff];
            const float hn   = fmaf(zv, hbar - hold, hold); // (1-z)h + z*hbar
            hT[hoff]  = hn;
            out[ooff] = hn;
            if (t == TT-1) out[(size_t)BS*TT*1024 + (size_t)bb*1024 + c0 + c] = hn;
        }
        grid.sync();
    }
}

extern "C" void kernel_launch(void* const* d_in, const int* in_sizes, int n_in,
                              void* d_out, int out_size, void* d_ws, size_t ws_size,
                              hipStream_t stream)
{
    const float* x   = (const float*)d_in[0];
    const float* h0  = (const float*)d_in[1];
    const float* w_z = (const float*)d_in[2];
    const float* w_r = (const float*)d_in[3];
    const float* w   = (const float*)d_in[4];
    const float* bZ  = (const float*)d_in[5];
    const float* bR  = (const float*)d_in[6];
    const float* bH  = (const float*)d_in[7];
    float* out = (float*)d_out;

    const size_t nBT = (size_t)BS*TT*1024;        // 33,554,432
    char* wsb = (char*)d_ws;
    unsigned short* xz16 = (unsigned short*)wsb;            // 64 MB
    unsigned short* xr16 = xz16 + nBT;                      // 64 MB
    float* hT  = (float*)(wsb + 2*nBT*sizeof(unsigned short));
    float* rhT = hT + HID*BS;

    p1_gemm<<<dim3(256,48), 256, 0, stream>>>(x, w_z, w_r, w, bZ, bR, bH,
                                              xz16, xr16, out);

    const float* h0a = h0; const float* wza = w_z; const float* wra = w_r;
    const float* wa = w; const unsigned short* xza = xz16; const unsigned short* xra = xr16;
    float* hTa = hT; float* rhTa = rhT; float* outa = out;
    void* args[] = { (void*)&h0a, (void*)&wza, (void*)&wra, (void*)&wa,
                     (void*)&xza, (void*)&xra, (void*)&hTa, (void*)&rhTa, (void*)&outa };
    hipLaunchCooperativeKernel((void*)scan_persist, dim3(NWG), dim3(NTHR),
                               args, 0, stream);
}